// Round 13
// baseline (219.777 us; speedup 1.0000x reference)
//
#include <hip/hip_runtime.h>
#include <hip/hip_bf16.h>

using bf16 = __hip_bfloat16;
typedef __bf16 bf16x8 __attribute__((ext_vector_type(8)));
typedef float floatx4 __attribute__((ext_vector_type(4)));

// Problem dims
constexpr int BB = 4, SS = 2048, DIN = 512, DKK = 2048, DVV = 64;
constexpr int ROWS = BB * SS;          // 8192
constexpr int NQKV = 4224;             // q(2048) | k(2048) | v(64) | pad(64)

// ---- workspace layout (bytes) ----
constexpr size_t XB_OFF = 0;                                   // bf16 xb [8192][512]
constexpr size_t WT_OFF = XB_OFF + (size_t)ROWS * DIN * 2;     // bf16 wt [4224][512]; later fp32 stats
constexpr size_t VT_OFF = WT_OFF + (size_t)NQKV * DIN * 2;     // bf16 vt [4][64][2048]
constexpr size_t QK_OFF = VT_OFF + (size_t)BB * DVV * SS * 2;  // bf16 qkv [8192][4224]
constexpr size_t SC_OFF = QK_OFF + (size_t)ROWS * NQKV * 2;    // bf16 O' partials [4][16][2048][64]

__device__ __forceinline__ void async_copy16(const bf16* g, const unsigned short* l) {
    __builtin_amdgcn_global_load_lds((const __attribute__((address_space(1))) void*)g,
                                     (__attribute__((address_space(3))) void*)l, 16, 0, 0);
}

// ---------------- convert x -> bf16 (vectorized x4) ----------------
__global__ __launch_bounds__(256) void convert_x(const float* __restrict__ in,
                                                 bf16* __restrict__ out, int n4) {
    int i = blockIdx.x * 256 + threadIdx.x;
    if (i >= n4) return;
    float4 v = reinterpret_cast<const float4*>(in)[i];
    union { bf16 h[4]; ushort4 u; } cv;
    cv.h[0] = __float2bfloat16(v.x);
    cv.h[1] = __float2bfloat16(v.y);
    cv.h[2] = __float2bfloat16(v.z);
    cv.h[3] = __float2bfloat16(v.w);
    reinterpret_cast<ushort4*>(out)[i] = cv.u;
}

// ------------- LDS-tiled transpose: wt[4224][512] = [Wq|Wk|Wv|0]^T -------------
__global__ __launch_bounds__(256) void transpose_w(const float* __restrict__ Wq,
                                                   const float* __restrict__ Wk,
                                                   const float* __restrict__ Wv,
                                                   bf16* __restrict__ wt) {
    int n0 = blockIdx.x * 32;               // 132 n-tiles
    int k0 = blockIdx.y * 32;
    __shared__ float tile[32][33];
    int tid = threadIdx.x;
    int nn = tid & 31, kk8 = tid >> 5;
    const float* src; int col, ld;
    if (n0 < 2048)      { src = Wq; col = n0 + nn;        ld = 2048; }
    else if (n0 < 4096) { src = Wk; col = n0 - 2048 + nn; ld = 2048; }
    else if (n0 < 4160) { src = Wv; col = n0 - 4096 + nn; ld = 64;   }
    else                { src = nullptr; col = 0; ld = 0; }
    #pragma unroll
    for (int p = 0; p < 4; ++p) {
        int k = p * 8 + kk8;
        tile[k][nn] = src ? src[(long long)(k0 + k) * ld + col] : 0.f;
    }
    __syncthreads();
    int kk = tid & 31, nn8 = tid >> 5;
    #pragma unroll
    for (int p = 0; p < 4; ++p) {
        int n = p * 8 + nn8;
        wt[(long long)(n0 + n) * 512 + k0 + kk] = __float2bfloat16(tile[kk][n]);
    }
}

// ------------- vt[b][j][s] = qkv[b*2048+s][4096+j] (LDS-tiled 64x64) -------------
__global__ __launch_bounds__(256) void transpose_v(const bf16* __restrict__ qkv,
                                                   bf16* __restrict__ vt) {
    int rb = blockIdx.x;                  // 128 blocks of 64 s-rows
    int b = rb >> 5;
    int s0 = (rb & 31) * 64;
    __shared__ unsigned short tile[64][72];
    int tid = threadIdx.x;
    int rowInPass = tid >> 3;
    int c16 = (tid & 7) * 8;
    const bf16* src = qkv + ((long long)(b * SS + s0)) * NQKV + 4096;
    #pragma unroll
    for (int p = 0; p < 2; ++p) {
        int r = p * 32 + rowInPass;
        union { uint4 q; unsigned short u[8]; } ld;
        ld.q = *reinterpret_cast<const uint4*>(src + (long long)r * NQKV + c16);
        #pragma unroll
        for (int j = 0; j < 8; ++j) tile[r][c16 + j] = ld.u[j];
    }
    __syncthreads();
    int j = tid >> 2;
    int sOff = (tid & 3) * 16;
    union { uint4 q[2]; unsigned short u[16]; } st;
    #pragma unroll
    for (int i = 0; i < 16; ++i) st.u[i] = tile[sOff + i][j];
    bf16* dst = vt + ((long long)b * DVV + j) * SS + s0 + sOff;
    *reinterpret_cast<uint4*>(dst) = st.q[0];
    *reinterpret_cast<uint4*>(dst + 8) = st.q[1];
}

// ---------------- projection GEMM: round-10 form verbatim (best measured) ----------------
// 4-wave 128x128, BK=64, single buffer, 8 K-iters, 2112 blocks, inline addressing.
__global__ __launch_bounds__(256) void gemm_proj(const bf16* __restrict__ A,
                                                 const bf16* __restrict__ Bt,
                                                 bf16* __restrict__ C,
                                                 int K, int lda, int ldb, int ldc) {
    __shared__ __align__(16) unsigned short As[128 * 64];   // 16 KB
    __shared__ __align__(16) unsigned short Bs[128 * 64];   // 16 KB

    const int tid = threadIdx.x;
    const int lane = tid & 63, wave = tid >> 6;
    const long long m0 = (long long)blockIdx.y * 128;
    const long long n0 = (long long)blockIdx.x * 128;

    const int rIn = lane >> 3;                   // row within 8-row 1KB issue
    const int cSwz = ((lane & 7) ^ rIn) * 8;     // swizzled global chunk (bf16 elems)
    const int wm0 = (wave >> 1) * 64, wn0 = (wave & 1) * 64;   // wave-tile 64x64
    const int l15 = lane & 15, quad = lane >> 4;
    const int sw7 = l15 & 7;

    floatx4 acc[4][4] = {};

    for (int k0 = 0; k0 < K; k0 += 64) {         // 8 iterations at K=512
        #pragma unroll
        for (int t0 = 0; t0 < 8; ++t0) {
            int t = t0 * 4 + wave;
            if (t < 16)
                async_copy16(A + (m0 + t * 8 + rIn) * (long long)lda + k0 + cSwz,
                             &As[t * 512]);
            else
                async_copy16(Bt + (n0 + (t - 16) * 8 + rIn) * (long long)ldb + k0 + cSwz,
                             &Bs[(t - 16) * 512]);
        }
        __syncthreads();
        #pragma unroll
        for (int sk = 0; sk < 2; ++sk) {
            const int rchunk = (((sk << 2) | quad) ^ sw7) * 8;
            bf16x8 af[4], bfr[4];
            #pragma unroll
            for (int mi = 0; mi < 4; ++mi)
                af[mi] = *reinterpret_cast<const bf16x8*>(&As[(wm0 + mi * 16 + l15) * 64 + rchunk]);
            #pragma unroll
            for (int ni = 0; ni < 4; ++ni)
                bfr[ni] = *reinterpret_cast<const bf16x8*>(&Bs[(wn0 + ni * 16 + l15) * 64 + rchunk]);
            #pragma unroll
            for (int mi = 0; mi < 4; ++mi)
                #pragma unroll
                for (int ni = 0; ni < 4; ++ni)
                    acc[mi][ni] = __builtin_amdgcn_mfma_f32_16x16x32_bf16(af[mi], bfr[ni],
                                                                          acc[mi][ni], 0, 0, 0);
        }
        __syncthreads();
    }

    #pragma unroll
    for (int mi = 0; mi < 4; ++mi) {
        long long row0 = m0 + wm0 + mi * 16 + quad * 4;
        #pragma unroll
        for (int ni = 0; ni < 4; ++ni) {
            long long col = n0 + wn0 + ni * 16 + l15;
            #pragma unroll
            for (int r = 0; r < 4; ++r)
                C[(row0 + r) * (long long)ldc + col] = __float2bfloat16(acc[mi][ni][r]);
        }
    }
}

// ---------------- fused causal attention tile (round-8 form verbatim: 81.8 µs measured) ----------
__global__ __launch_bounds__(512) void attn_fused(const bf16* __restrict__ qkv,
                                                  const bf16* __restrict__ vt,
                                                  bf16* __restrict__ part,
                                                  float* __restrict__ stats) {
    constexpr int BK = 64;
    constexpr float SCALE = 0.022097086912079608f;   // 1/sqrt(2048)

    __shared__ __align__(16) char smem[65536];
    unsigned short* As = (unsigned short*)smem;             // [2][8192] QK staging
    unsigned short* Bs = (unsigned short*)(smem + 32768);   // [2][8192]
    unsigned short* Ps = (unsigned short*)smem;             // [128][136] P~ (overlay, post-QK)
    unsigned short* Vs = (unsigned short*)(smem + 34816);   // [64][136]  V chunk
    float* smax = (float*)(smem + 52224);                   // [128][2]
    float* ssum = (float*)(smem + 53248);                   // [128][2]

    // rectangular causal fold
    int T2 = (int)gridDim.y * 2;
    int xx = blockIdx.x, rr = blockIdx.y;
    int bx, by;
    if (xx <= rr) { by = rr; bx = xx; }
    else          { by = T2 - 1 - rr; bx = xx - rr - 1; }
    const int b = blockIdx.z;

    const bf16* A  = qkv + (long long)b * SS * NQKV;         // q rows
    const bf16* Bt = A + DKK;                                // k rows

    const int tid = threadIdx.x;
    const int lane = tid & 63, wave = tid >> 6;
    const long long m0 = (long long)by * 128;
    const long long n0 = (long long)bx * 128;

    const int rIn = lane >> 3;
    const int cSwz = ((lane & 7) ^ rIn) * 8;
    const int wm0 = (wave >> 1) * 32, wn0 = (wave & 1) * 64;
    const int l15 = lane & 15, quad = lane >> 4;
    const int sw7 = l15 & 7;

    floatx4 acc[2][4] = {};

    auto issue = [&](int buf, int k0) {
        #pragma unroll
        for (int t0 = 0; t0 < 4; ++t0) {
            int t = t0 * 8 + wave;
            if (t < 16)
                async_copy16(A + (m0 + t * 8 + rIn) * (long long)NQKV + k0 + cSwz,
                             &As[buf * 8192 + t * 512]);
            else
                async_copy16(Bt + (n0 + (t - 16) * 8 + rIn) * (long long)NQKV + k0 + cSwz,
                             &Bs[buf * 8192 + (t - 16) * 512]);
        }
    };

    issue(0, 0);
    __syncthreads();
    for (int it = 0; it < DKK / BK; ++it) {
        const int cur = it & 1;
        if (it + 1 < DKK / BK) issue(cur ^ 1, (it + 1) * BK);
        #pragma unroll
        for (int sk = 0; sk < 2; ++sk) {
            const int rchunk = ((sk << 2) | quad) ^ sw7;
            bf16x8 af[2], bfr[4];
            #pragma unroll
            for (int mi = 0; mi < 2; ++mi)
                af[mi] = *reinterpret_cast<const bf16x8*>(
                    &As[cur * 8192 + (wm0 + mi * 16 + l15) * BK + rchunk * 8]);
            #pragma unroll
            for (int ni = 0; ni < 4; ++ni)
                bfr[ni] = *reinterpret_cast<const bf16x8*>(
                    &Bs[cur * 8192 + (wn0 + ni * 16 + l15) * BK + rchunk * 8]);
            #pragma unroll
            for (int mi = 0; mi < 2; ++mi)
                #pragma unroll
                for (int ni = 0; ni < 4; ++ni)
                    acc[mi][ni] = __builtin_amdgcn_mfma_f32_16x16x32_bf16(af[mi], bfr[ni],
                                                                          acc[mi][ni], 0, 0, 0);
        }
        __syncthreads();
    }
    // QK done. S in acc, C-layout: row=wm0+mi*16+quad*4+r, col=wn0+ni*16+l15.

    // scale + causal mask (diagonal tile only)
    #pragma unroll
    for (int mi = 0; mi < 2; ++mi)
        #pragma unroll
        for (int ni = 0; ni < 4; ++ni)
            #pragma unroll
            for (int r = 0; r < 4; ++r) {
                float v = acc[mi][ni][r] * SCALE;
                if (bx == by) {
                    int row = wm0 + mi * 16 + quad * 4 + r;
                    int col = wn0 + ni * 16 + l15;
                    if (col > row) v = -INFINITY;
                }
                acc[mi][ni][r] = v;
            }

    // row max within tile
    float rmax[2][4];
    #pragma unroll
    for (int mi = 0; mi < 2; ++mi)
        #pragma unroll
        for (int r = 0; r < 4; ++r) {
            float m = fmaxf(fmaxf(acc[mi][0][r], acc[mi][1][r]),
                            fmaxf(acc[mi][2][r], acc[mi][3][r]));
            #pragma unroll
            for (int msk = 8; msk >= 1; msk >>= 1) m = fmaxf(m, __shfl_xor(m, msk));
            rmax[mi][r] = m;
            if (l15 == 0) smax[(wm0 + mi * 16 + quad * 4 + r) * 2 + (wave & 1)] = m;
        }
    __syncthreads();
    #pragma unroll
    for (int mi = 0; mi < 2; ++mi)
        #pragma unroll
        for (int r = 0; r < 4; ++r) {
            int row = wm0 + mi * 16 + quad * 4 + r;
            rmax[mi][r] = fmaxf(smax[row * 2], smax[row * 2 + 1]);
        }

    // exp + row sums; write P~ to padded LDS
    #pragma unroll
    for (int mi = 0; mi < 2; ++mi)
        #pragma unroll
        for (int r = 0; r < 4; ++r) {
            float s = 0.f;
            #pragma unroll
            for (int ni = 0; ni < 4; ++ni) {
                float p = __expf(acc[mi][ni][r] - rmax[mi][r]);
                acc[mi][ni][r] = p;
                s += p;
            }
            #pragma unroll
            for (int msk = 8; msk >= 1; msk >>= 1) s += __shfl_xor(s, msk);
            if (l15 == 0) ssum[(wm0 + mi * 16 + quad * 4 + r) * 2 + (wave & 1)] = s;
        }
    #pragma unroll
    for (int mi = 0; mi < 2; ++mi) {
        int row = wm0 + mi * 16 + quad * 4;
        #pragma unroll
        for (int ni = 0; ni < 4; ++ni) {
            int col = wn0 + ni * 16 + l15;
            #pragma unroll
            for (int r = 0; r < 4; ++r)
                Ps[(row + r) * 136 + col] = (unsigned short)__bfloat16_as_ushort(__float2bfloat16(acc[mi][ni][r]));
        }
    }

    // stage V chunk: Vs[j][k] = vt[b][j][n0+k], xor-swizzled 16B chunks
    #pragma unroll
    for (int p = 0; p < 2; ++p) {
        int j = (tid >> 4) + p * 32;
        int ch = tid & 15;
        uint4 v = *reinterpret_cast<const uint4*>(
            vt + ((long long)b * DVV + j) * SS + n0 + ch * 8);
        *reinterpret_cast<uint4*>(&Vs[j * 136 + ((ch ^ (j & 7)) * 8)]) = v;
    }
    __syncthreads();

    // per-row stats out (m, l)
    if (tid < 128) {
        float m = fmaxf(smax[tid * 2], smax[tid * 2 + 1]);
        float l = ssum[tid * 2] + ssum[tid * 2 + 1];
        long long o = (((long long)b * 16 + bx) * SS + m0 + tid) * 2;
        stats[o] = m;
        stats[o + 1] = l;
    }

    // O' = P~ . V  (M=128, N=64, K=128): wave-tile 16 rows x 64 cols
    const int wmv = wave * 16;
    floatx4 accO[4] = {};
    #pragma unroll
    for (int sk = 0; sk < 4; ++sk) {
        bf16x8 af = *reinterpret_cast<const bf16x8*>(
            &Ps[(wmv + l15) * 136 + sk * 32 + quad * 8]);
        #pragma unroll
        for (int ni = 0; ni < 4; ++ni) {
            bf16x8 bfv = *reinterpret_cast<const bf16x8*>(
                &Vs[(ni * 16 + l15) * 136 + ((((sk << 2) | quad)) ^ sw7) * 8]);
            accO[ni] = __builtin_amdgcn_mfma_f32_16x16x32_bf16(af, bfv, accO[ni], 0, 0, 0);
        }
    }
    #pragma unroll
    for (int ni = 0; ni < 4; ++ni)
        #pragma unroll
        for (int r = 0; r < 4; ++r)
            part[(((long long)b * 16 + bx) * SS + m0 + wmv + quad * 4 + r) * 64 + ni * 16 + l15]
                = __float2bfloat16(accO[ni][r]);
}

// ---------------- combine k-tile partials (vectorized x8 bf16 loads) ----------------
__global__ __launch_bounds__(256) void combine(const bf16* __restrict__ part,
                                               const float* __restrict__ stats,
                                               float* __restrict__ out) {
    int tid = blockIdx.x * 256 + threadIdx.x;   // over 8192*8
    int row = tid >> 3;
    int col8 = (tid & 7) * 8;
    int b = row >> 11, s = row & (SS - 1);
    int nt = (s >> 7) + 1;                      // live k-tiles for this row

    float m[16], l[16], M = -INFINITY;
    #pragma unroll
    for (int t = 0; t < 16; ++t)
        if (t < nt) {
            long long o = (((long long)b * 16 + t) * SS + s) * 2;
            m[t] = stats[o];
            l[t] = stats[o + 1];
            M = fmaxf(M, m[t]);
        }
    float O[8] = {};
    float L = 0.f;
    #pragma unroll
    for (int t = 0; t < 16; ++t)
        if (t < nt) {
            float wgt = __expf(m[t] - M);
            L += wgt * l[t];
            union { uint4 q; unsigned short u[8]; } ld;
            ld.q = *reinterpret_cast<const uint4*>(
                part + (((long long)b * 16 + t) * SS + s) * 64 + col8);
            #pragma unroll
            for (int j = 0; j < 8; ++j)
                O[j] += wgt * __uint_as_float((unsigned)ld.u[j] << 16);
        }
    float rinv = 1.0f / L;
    float4 o0 = {O[0] * rinv, O[1] * rinv, O[2] * rinv, O[3] * rinv};
    float4 o1 = {O[4] * rinv, O[5] * rinv, O[6] * rinv, O[7] * rinv};
    float4* dst = reinterpret_cast<float4*>(out + (long long)row * 64 + col8);
    dst[0] = o0;
    dst[1] = o1;
}

extern "C" void kernel_launch(void* const* d_in, const int* in_sizes, int n_in,
                              void* d_out, int out_size, void* d_ws, size_t ws_size,
                              hipStream_t stream) {
    const float* x  = (const float*)d_in[0];
    const float* Wq = (const float*)d_in[1];
    const float* Wk = (const float*)d_in[2];
    const float* Wv = (const float*)d_in[3];
    float* out = (float*)d_out;

    char* w = (char*)d_ws;
    bf16* xb  = (bf16*)(w + XB_OFF);
    bf16* wt  = (bf16*)(w + WT_OFF);
    bf16* vt  = (bf16*)(w + VT_OFF);
    bf16* qkv = (bf16*)(w + QK_OFF);
    bf16* part = (bf16*)(w + SC_OFF);      // [4][16][2048][64] bf16 O' partials
    float* stats = (float*)(w + WT_OFF);   // alias: wt dead after projection

    // 1. conversions / transposes
    convert_x<<<ROWS * DIN / 4 / 256, 256, 0, stream>>>(x, xb, ROWS * DIN / 4);
    transpose_w<<<dim3(NQKV / 32, DIN / 32), 256, 0, stream>>>(Wq, Wk, Wv, wt);

    // 2. fused q|k|v projection (round-10 best: 4-wave 128x128, BK=64 single, 2112 blocks)
    gemm_proj<<<dim3(NQKV / 128, ROWS / 128, 1), 256, 0, stream>>>(
        xb, wt, qkv, DIN, DIN, DIN, NQKV);

    // 2b. vt from qkv v-columns
    transpose_v<<<ROWS / 64, 256, 0, stream>>>(qkv, vt);

    // 3. fused attention tiles (round-8 best: QK^T BK=64 dbuf + softmax + P~V), causal fold
    attn_fused<<<dim3(SS / 128 + 1, SS / 256, BB), 512, 0, stream>>>(qkv, vt, part, stats);

    // 4. combine partials -> out
    combine<<<ROWS * 8 / 256, 256, 0, stream>>>(part, stats, out);
}

// Round 14
// 151.744 us; speedup vs baseline: 1.4483x; 1.4483x over previous
//
#include <hip/hip_runtime.h>
#include <hip/hip_bf16.h>

using bf16 = __hip_bfloat16;
typedef __bf16 bf16x8 __attribute__((ext_vector_type(8)));
typedef float floatx4 __attribute__((ext_vector_type(4)));

// Problem dims
constexpr int BB = 4, SS = 2048, DIN = 512, DKK = 2048, DVV = 64;
constexpr int ROWS = BB * SS;          // 8192
constexpr int LDY = 640;               // yv row: y(512) | v(64) | pad(64, garbage ok)

// ---- workspace layout (bytes) ----
// scores = x·(Wq Wk^T)·x^T: Mt[j][i] = sum_n Wk[j,n]Wq[i,n]; y = xb·Mt^T; scores = y·xb^T (K=512)
constexpr size_t XB_OFF  = 0;                          // bf16 xb  [8192][512]   (8 MB, live to the end)
constexpr size_t WQB_OFF = XB_OFF  + 8388608;          // bf16 wqb [512][2048]   (2 MB)
constexpr size_t WKB_OFF = WQB_OFF + 2097152;          // bf16 wkb [512][2048]   (2 MB)
constexpr size_t WT2_OFF = WKB_OFF + 2097152;          // bf16 wt2 [640][512]: rows 0..511 Mt, 512..575 Wv^T, 576..639 garbage
constexpr size_t MTP_OFF = WT2_OFF + 655360;           // fp32 mt partials [8][512][512] (8 MB)
constexpr size_t YV_OFF  = MTP_OFF + 8388608;          // bf16 yv  [8192][640]   (10 MB)
constexpr size_t VT_OFF  = YV_OFF  + 10485760;         // bf16 vt  [4][64][2048] (1 MB)
constexpr size_t PRT_OFF = VT_OFF  + 1048576;          // bf16 O' partials [4][16][2048][64] (16 MB)
constexpr size_t STA_OFF = PRT_OFF + 16777216;         // fp32 stats [4][16][2048][2] (1 MB)

__device__ __forceinline__ void async_copy16(const bf16* g, const unsigned short* l) {
    __builtin_amdgcn_global_load_lds((const __attribute__((address_space(1))) void*)g,
                                     (__attribute__((address_space(3))) void*)l, 16, 0, 0);
}

// ---------------- convert x -> bf16 (vectorized x4) ----------------
__global__ __launch_bounds__(256) void convert_x(const float* __restrict__ in,
                                                 bf16* __restrict__ out, int n4) {
    int i = blockIdx.x * 256 + threadIdx.x;
    if (i >= n4) return;
    float4 v = reinterpret_cast<const float4*>(in)[i];
    union { bf16 h[4]; ushort4 u; } cv;
    cv.h[0] = __float2bfloat16(v.x);
    cv.h[1] = __float2bfloat16(v.y);
    cv.h[2] = __float2bfloat16(v.z);
    cv.h[3] = __float2bfloat16(v.w);
    reinterpret_cast<ushort4*>(out)[i] = cv.u;
}

// ---------------- convert Wq|Wk -> bf16 (straight copy, no transpose needed) ----------------
__global__ __launch_bounds__(256) void convert_wqk(const float* __restrict__ Wq,
                                                   const float* __restrict__ Wk,
                                                   bf16* __restrict__ wqb,
                                                   bf16* __restrict__ wkb) {
    int i = blockIdx.x * 256 + threadIdx.x;          // over 2*1048576/4 = 524288 groups
    const float* src = (i < 262144) ? Wq : Wk;
    bf16* dst = (i < 262144) ? wqb : wkb;
    int j = (i < 262144) ? i : i - 262144;
    float4 v = reinterpret_cast<const float4*>(src)[j];
    union { bf16 h[4]; ushort4 u; } cv;
    cv.h[0] = __float2bfloat16(v.x);
    cv.h[1] = __float2bfloat16(v.y);
    cv.h[2] = __float2bfloat16(v.z);
    cv.h[3] = __float2bfloat16(v.w);
    reinterpret_cast<ushort4*>(dst)[j] = cv.u;
}

// ------------- Wv [512][64] fp32 -> wt2 rows 512..575 as [64][512] bf16 (LDS tiled) -------------
__global__ __launch_bounds__(256) void transpose_wv(const float* __restrict__ Wv,
                                                    bf16* __restrict__ wt2) {
    int n0 = blockIdx.x * 32;               // 2 tiles over 64
    int k0 = blockIdx.y * 32;               // 16 tiles over 512
    __shared__ float tile[32][33];
    int tid = threadIdx.x;
    int nn = tid & 31, kk8 = tid >> 5;
    #pragma unroll
    for (int p = 0; p < 4; ++p) {
        int k = p * 8 + kk8;
        tile[k][nn] = Wv[(long long)(k0 + k) * 64 + n0 + nn];
    }
    __syncthreads();
    int kk = tid & 31, nn8 = tid >> 5;
    #pragma unroll
    for (int p = 0; p < 4; ++p) {
        int n = p * 8 + nn8;
        wt2[(long long)(512 + n0 + n) * 512 + k0 + kk] = __float2bfloat16(tile[kk][n]);
    }
}

// ---------------- Mt partial GEMM: Mt[j][i] = sum_n wkb[j][n]*wqb[i][n], split-K 8 ----------------
// gemm_proj structure (BK=64 single buffer), K-chunk=256 (4 iters), fp32 partial planes.
__global__ __launch_bounds__(256) void gemm_mt(const bf16* __restrict__ A,
                                               const bf16* __restrict__ Bt,
                                               float* __restrict__ Cp) {
    __shared__ __align__(16) unsigned short As[128 * 64];
    __shared__ __align__(16) unsigned short Bs[128 * 64];

    const int tid = threadIdx.x;
    const int lane = tid & 63, wave = tid >> 6;
    const long long m0 = (long long)blockIdx.y * 128;
    const long long n0 = (long long)blockIdx.x * 128;
    const int koff = blockIdx.z * 256;

    const int rIn = lane >> 3;
    const int cSwz = ((lane & 7) ^ rIn) * 8;
    const int wm0 = (wave >> 1) * 64, wn0 = (wave & 1) * 64;
    const int l15 = lane & 15, quad = lane >> 4;
    const int sw7 = l15 & 7;

    floatx4 acc[4][4] = {};

    for (int k0 = koff; k0 < koff + 256; k0 += 64) {
        #pragma unroll
        for (int t0 = 0; t0 < 8; ++t0) {
            int t = t0 * 4 + wave;
            if (t < 16)
                async_copy16(A + (m0 + t * 8 + rIn) * 2048LL + k0 + cSwz, &As[t * 512]);
            else
                async_copy16(Bt + (n0 + (t - 16) * 8 + rIn) * 2048LL + k0 + cSwz, &Bs[(t - 16) * 512]);
        }
        __syncthreads();
        #pragma unroll
        for (int sk = 0; sk < 2; ++sk) {
            const int rchunk = (((sk << 2) | quad) ^ sw7) * 8;
            bf16x8 af[4], bfr[4];
            #pragma unroll
            for (int mi = 0; mi < 4; ++mi)
                af[mi] = *reinterpret_cast<const bf16x8*>(&As[(wm0 + mi * 16 + l15) * 64 + rchunk]);
            #pragma unroll
            for (int ni = 0; ni < 4; ++ni)
                bfr[ni] = *reinterpret_cast<const bf16x8*>(&Bs[(wn0 + ni * 16 + l15) * 64 + rchunk]);
            #pragma unroll
            for (int mi = 0; mi < 4; ++mi)
                #pragma unroll
                for (int ni = 0; ni < 4; ++ni)
                    acc[mi][ni] = __builtin_amdgcn_mfma_f32_16x16x32_bf16(af[mi], bfr[ni],
                                                                          acc[mi][ni], 0, 0, 0);
        }
        __syncthreads();
    }

    float* C = Cp + (long long)blockIdx.z * 262144;
    #pragma unroll
    for (int mi = 0; mi < 4; ++mi) {
        long long row0 = m0 + wm0 + mi * 16 + quad * 4;
        #pragma unroll
        for (int ni = 0; ni < 4; ++ni) {
            long long col = n0 + wn0 + ni * 16 + l15;
            #pragma unroll
            for (int r = 0; r < 4; ++r)
                C[(row0 + r) * 512 + col] = acc[mi][ni][r];
        }
    }
}

// ---------------- reduce Mt partials -> wt2 rows 0..511 (bf16) ----------------
__global__ __launch_bounds__(256) void reduce_mt(const float4* __restrict__ part,
                                                 bf16* __restrict__ wt2) {
    int i = blockIdx.x * 256 + threadIdx.x;          // over 65536 float4 groups
    float4 s = {0.f, 0.f, 0.f, 0.f};
    #pragma unroll
    for (int t = 0; t < 8; ++t) {
        float4 a = part[(long long)t * 65536 + i];
        s.x += a.x; s.y += a.y; s.z += a.z; s.w += a.w;
    }
    union { bf16 h[4]; ushort4 u; } cv;
    cv.h[0] = __float2bfloat16(s.x);
    cv.h[1] = __float2bfloat16(s.y);
    cv.h[2] = __float2bfloat16(s.z);
    cv.h[3] = __float2bfloat16(s.w);
    reinterpret_cast<ushort4*>(wt2)[i] = cv.u;
}

// ---------------- yv GEMM: yv[8192][640] = xb . wt2^T  (round-10 proj structure verbatim) ----------
// Cols 0..511 = y = x·M (q·k collapsed), 512..575 = v = x·Wv, 576..639 garbage (never read).
__global__ __launch_bounds__(256) void gemm_proj(const bf16* __restrict__ A,
                                                 const bf16* __restrict__ Bt,
                                                 bf16* __restrict__ C,
                                                 int K, int lda, int ldb, int ldc) {
    __shared__ __align__(16) unsigned short As[128 * 64];
    __shared__ __align__(16) unsigned short Bs[128 * 64];

    const int tid = threadIdx.x;
    const int lane = tid & 63, wave = tid >> 6;
    const long long m0 = (long long)blockIdx.y * 128;
    const long long n0 = (long long)blockIdx.x * 128;

    const int rIn = lane >> 3;
    const int cSwz = ((lane & 7) ^ rIn) * 8;
    const int wm0 = (wave >> 1) * 64, wn0 = (wave & 1) * 64;
    const int l15 = lane & 15, quad = lane >> 4;
    const int sw7 = l15 & 7;

    floatx4 acc[4][4] = {};

    for (int k0 = 0; k0 < K; k0 += 64) {
        #pragma unroll
        for (int t0 = 0; t0 < 8; ++t0) {
            int t = t0 * 4 + wave;
            if (t < 16)
                async_copy16(A + (m0 + t * 8 + rIn) * (long long)lda + k0 + cSwz, &As[t * 512]);
            else
                async_copy16(Bt + (n0 + (t - 16) * 8 + rIn) * (long long)ldb + k0 + cSwz, &Bs[(t - 16) * 512]);
        }
        __syncthreads();
        #pragma unroll
        for (int sk = 0; sk < 2; ++sk) {
            const int rchunk = (((sk << 2) | quad) ^ sw7) * 8;
            bf16x8 af[4], bfr[4];
            #pragma unroll
            for (int mi = 0; mi < 4; ++mi)
                af[mi] = *reinterpret_cast<const bf16x8*>(&As[(wm0 + mi * 16 + l15) * 64 + rchunk]);
            #pragma unroll
            for (int ni = 0; ni < 4; ++ni)
                bfr[ni] = *reinterpret_cast<const bf16x8*>(&Bs[(wn0 + ni * 16 + l15) * 64 + rchunk]);
            #pragma unroll
            for (int mi = 0; mi < 4; ++mi)
                #pragma unroll
                for (int ni = 0; ni < 4; ++ni)
                    acc[mi][ni] = __builtin_amdgcn_mfma_f32_16x16x32_bf16(af[mi], bfr[ni],
                                                                          acc[mi][ni], 0, 0, 0);
        }
        __syncthreads();
    }

    #pragma unroll
    for (int mi = 0; mi < 4; ++mi) {
        long long row0 = m0 + wm0 + mi * 16 + quad * 4;
        #pragma unroll
        for (int ni = 0; ni < 4; ++ni) {
            long long col = n0 + wn0 + ni * 16 + l15;
            #pragma unroll
            for (int r = 0; r < 4; ++r)
                C[(row0 + r) * (long long)ldc + col] = __float2bfloat16(acc[mi][ni][r]);
        }
    }
}

// ------------- vt[b][j][s] = yv[b*2048+s][512+j] (LDS-tiled 64x64) -------------
__global__ __launch_bounds__(256) void transpose_v(const bf16* __restrict__ yv,
                                                   bf16* __restrict__ vt) {
    int rb = blockIdx.x;                  // 128 blocks of 64 s-rows
    int b = rb >> 5;
    int s0 = (rb & 31) * 64;
    __shared__ unsigned short tile[64][72];
    int tid = threadIdx.x;
    int rowInPass = tid >> 3;
    int c16 = (tid & 7) * 8;
    const bf16* src = yv + ((long long)(b * SS + s0)) * LDY + 512;
    #pragma unroll
    for (int p = 0; p < 2; ++p) {
        int r = p * 32 + rowInPass;
        union { uint4 q; unsigned short u[8]; } ld;
        ld.q = *reinterpret_cast<const uint4*>(src + (long long)r * LDY + c16);
        #pragma unroll
        for (int j = 0; j < 8; ++j) tile[r][c16 + j] = ld.u[j];
    }
    __syncthreads();
    int j = tid >> 2;
    int sOff = (tid & 3) * 16;
    union { uint4 q[2]; unsigned short u[16]; } st;
    #pragma unroll
    for (int i = 0; i < 16; ++i) st.u[i] = tile[sOff + i][j];
    bf16* dst = vt + ((long long)b * DVV + j) * SS + s0 + sOff;
    *reinterpret_cast<uint4*>(dst) = st.q[0];
    *reinterpret_cast<uint4*>(dst + 8) = st.q[1];
}

// ---------------- fused causal attention tile (round-8 body, K=512: scores = y·x^T) ----------------
__global__ __launch_bounds__(512) void attn_fused(const bf16* __restrict__ yv,
                                                  const bf16* __restrict__ xb,
                                                  const bf16* __restrict__ vt,
                                                  bf16* __restrict__ part,
                                                  float* __restrict__ stats) {
    constexpr int BK = 64;
    constexpr float SCALE = 0.022097086912079608f;   // 1/sqrt(2048) — dim_k unchanged

    __shared__ __align__(16) char smem[65536];
    unsigned short* As = (unsigned short*)smem;             // [2][8192] QK staging
    unsigned short* Bs = (unsigned short*)(smem + 32768);   // [2][8192]
    unsigned short* Ps = (unsigned short*)smem;             // [128][136] P~ (overlay, post-QK)
    unsigned short* Vs = (unsigned short*)(smem + 34816);   // [64][136]  V chunk
    float* smax = (float*)(smem + 52224);                   // [128][2]
    float* ssum = (float*)(smem + 53248);                   // [128][2]

    // rectangular causal fold
    int T2 = (int)gridDim.y * 2;
    int xx = blockIdx.x, rr = blockIdx.y;
    int bx, by;
    if (xx <= rr) { by = rr; bx = xx; }
    else          { by = T2 - 1 - rr; bx = xx - rr - 1; }
    const int b = blockIdx.z;

    const bf16* A  = yv + (long long)b * SS * LDY;           // y rows (q role)
    const bf16* Bt = xb + (long long)b * SS * 512;           // x rows (k role)

    const int tid = threadIdx.x;
    const int lane = tid & 63, wave = tid >> 6;
    const long long m0 = (long long)by * 128;
    const long long n0 = (long long)bx * 128;

    const int rIn = lane >> 3;
    const int cSwz = ((lane & 7) ^ rIn) * 8;
    const int wm0 = (wave >> 1) * 32, wn0 = (wave & 1) * 64;
    const int l15 = lane & 15, quad = lane >> 4;
    const int sw7 = l15 & 7;

    floatx4 acc[2][4] = {};

    auto issue = [&](int buf, int k0) {
        #pragma unroll
        for (int t0 = 0; t0 < 4; ++t0) {
            int t = t0 * 8 + wave;
            if (t < 16)
                async_copy16(A + (m0 + t * 8 + rIn) * (long long)LDY + k0 + cSwz,
                             &As[buf * 8192 + t * 512]);
            else
                async_copy16(Bt + (n0 + (t - 16) * 8 + rIn) * 512LL + k0 + cSwz,
                             &Bs[buf * 8192 + (t - 16) * 512]);
        }
    };

    issue(0, 0);
    __syncthreads();
    for (int it = 0; it < DIN / BK; ++it) {      // 8 iterations (K=512)
        const int cur = it & 1;
        if (it + 1 < DIN / BK) issue(cur ^ 1, (it + 1) * BK);
        #pragma unroll
        for (int sk = 0; sk < 2; ++sk) {
            const int rchunk = ((sk << 2) | quad) ^ sw7;
            bf16x8 af[2], bfr[4];
            #pragma unroll
            for (int mi = 0; mi < 2; ++mi)
                af[mi] = *reinterpret_cast<const bf16x8*>(
                    &As[cur * 8192 + (wm0 + mi * 16 + l15) * BK + rchunk * 8]);
            #pragma unroll
            for (int ni = 0; ni < 4; ++ni)
                bfr[ni] = *reinterpret_cast<const bf16x8*>(
                    &Bs[cur * 8192 + (wn0 + ni * 16 + l15) * BK + rchunk * 8]);
            #pragma unroll
            for (int mi = 0; mi < 2; ++mi)
                #pragma unroll
                for (int ni = 0; ni < 4; ++ni)
                    acc[mi][ni] = __builtin_amdgcn_mfma_f32_16x16x32_bf16(af[mi], bfr[ni],
                                                                          acc[mi][ni], 0, 0, 0);
        }
        __syncthreads();
    }
    // QK done. S in acc, C-layout: row=wm0+mi*16+quad*4+r, col=wn0+ni*16+l15.

    // scale + causal mask (diagonal tile only)
    #pragma unroll
    for (int mi = 0; mi < 2; ++mi)
        #pragma unroll
        for (int ni = 0; ni < 4; ++ni)
            #pragma unroll
            for (int r = 0; r < 4; ++r) {
                float v = acc[mi][ni][r] * SCALE;
                if (bx == by) {
                    int row = wm0 + mi * 16 + quad * 4 + r;
                    int col = wn0 + ni * 16 + l15;
                    if (col > row) v = -INFINITY;
                }
                acc[mi][ni][r] = v;
            }

    // row max within tile
    float rmax[2][4];
    #pragma unroll
    for (int mi = 0; mi < 2; ++mi)
        #pragma unroll
        for (int r = 0; r < 4; ++r) {
            float m = fmaxf(fmaxf(acc[mi][0][r], acc[mi][1][r]),
                            fmaxf(acc[mi][2][r], acc[mi][3][r]));
            #pragma unroll
            for (int msk = 8; msk >= 1; msk >>= 1) m = fmaxf(m, __shfl_xor(m, msk));
            rmax[mi][r] = m;
            if (l15 == 0) smax[(wm0 + mi * 16 + quad * 4 + r) * 2 + (wave & 1)] = m;
        }
    __syncthreads();
    #pragma unroll
    for (int mi = 0; mi < 2; ++mi)
        #pragma unroll
        for (int r = 0; r < 4; ++r) {
            int row = wm0 + mi * 16 + quad * 4 + r;
            rmax[mi][r] = fmaxf(smax[row * 2], smax[row * 2 + 1]);
        }

    // exp + row sums; write P~ to padded LDS
    #pragma unroll
    for (int mi = 0; mi < 2; ++mi)
        #pragma unroll
        for (int r = 0; r < 4; ++r) {
            float s = 0.f;
            #pragma unroll
            for (int ni = 0; ni < 4; ++ni) {
                float p = __expf(acc[mi][ni][r] - rmax[mi][r]);
                acc[mi][ni][r] = p;
                s += p;
            }
            #pragma unroll
            for (int msk = 8; msk >= 1; msk >>= 1) s += __shfl_xor(s, msk);
            if (l15 == 0) ssum[(wm0 + mi * 16 + quad * 4 + r) * 2 + (wave & 1)] = s;
        }
    #pragma unroll
    for (int mi = 0; mi < 2; ++mi) {
        int row = wm0 + mi * 16 + quad * 4;
        #pragma unroll
        for (int ni = 0; ni < 4; ++ni) {
            int col = wn0 + ni * 16 + l15;
            #pragma unroll
            for (int r = 0; r < 4; ++r)
                Ps[(row + r) * 136 + col] = (unsigned short)__bfloat16_as_ushort(__float2bfloat16(acc[mi][ni][r]));
        }
    }

    // stage V chunk: Vs[j][k] = vt[b][j][n0+k], xor-swizzled 16B chunks
    #pragma unroll
    for (int p = 0; p < 2; ++p) {
        int j = (tid >> 4) + p * 32;
        int ch = tid & 15;
        uint4 v = *reinterpret_cast<const uint4*>(
            vt + ((long long)b * DVV + j) * SS + n0 + ch * 8);
        *reinterpret_cast<uint4*>(&Vs[j * 136 + ((ch ^ (j & 7)) * 8)]) = v;
    }
    __syncthreads();

    // per-row stats out (m, l)
    if (tid < 128) {
        float m = fmaxf(smax[tid * 2], smax[tid * 2 + 1]);
        float l = ssum[tid * 2] + ssum[tid * 2 + 1];
        long long o = (((long long)b * 16 + bx) * SS + m0 + tid) * 2;
        stats[o] = m;
        stats[o + 1] = l;
    }

    // O' = P~ . V  (M=128, N=64, K=128): wave-tile 16 rows x 64 cols
    const int wmv = wave * 16;
    floatx4 accO[4] = {};
    #pragma unroll
    for (int sk = 0; sk < 4; ++sk) {
        bf16x8 af = *reinterpret_cast<const bf16x8*>(
            &Ps[(wmv + l15) * 136 + sk * 32 + quad * 8]);
        #pragma unroll
        for (int ni = 0; ni < 4; ++ni) {
            bf16x8 bfv = *reinterpret_cast<const bf16x8*>(
                &Vs[(ni * 16 + l15) * 136 + ((((sk << 2) | quad)) ^ sw7) * 8]);
            accO[ni] = __builtin_amdgcn_mfma_f32_16x16x32_bf16(af, bfv, accO[ni], 0, 0, 0);
        }
    }
    #pragma unroll
    for (int ni = 0; ni < 4; ++ni)
        #pragma unroll
        for (int r = 0; r < 4; ++r)
            part[(((long long)b * 16 + bx) * SS + m0 + wmv + quad * 4 + r) * 64 + ni * 16 + l15]
                = __float2bfloat16(accO[ni][r]);
}

// ---------------- combine k-tile partials (vectorized x8 bf16 loads) ----------------
__global__ __launch_bounds__(256) void combine(const bf16* __restrict__ part,
                                               const float* __restrict__ stats,
                                               float* __restrict__ out) {
    int tid = blockIdx.x * 256 + threadIdx.x;   // over 8192*8
    int row = tid >> 3;
    int col8 = (tid & 7) * 8;
    int b = row >> 11, s = row & (SS - 1);
    int nt = (s >> 7) + 1;                      // live k-tiles for this row

    float m[16], l[16], M = -INFINITY;
    #pragma unroll
    for (int t = 0; t < 16; ++t)
        if (t < nt) {
            long long o = (((long long)b * 16 + t) * SS + s) * 2;
            m[t] = stats[o];
            l[t] = stats[o + 1];
            M = fmaxf(M, m[t]);
        }
    float O[8] = {};
    float L = 0.f;
    #pragma unroll
    for (int t = 0; t < 16; ++t)
        if (t < nt) {
            float wgt = __expf(m[t] - M);
            L += wgt * l[t];
            union { uint4 q; unsigned short u[8]; } ld;
            ld.q = *reinterpret_cast<const uint4*>(
                part + (((long long)b * 16 + t) * SS + s) * 64 + col8);
            #pragma unroll
            for (int j = 0; j < 8; ++j)
                O[j] += wgt * __uint_as_float((unsigned)ld.u[j] << 16);
        }
    float rinv = 1.0f / L;
    float4 o0 = {O[0] * rinv, O[1] * rinv, O[2] * rinv, O[3] * rinv};
    float4 o1 = {O[4] * rinv, O[5] * rinv, O[6] * rinv, O[7] * rinv};
    float4* dst = reinterpret_cast<float4*>(out + (long long)row * 64 + col8);
    dst[0] = o0;
    dst[1] = o1;
}

extern "C" void kernel_launch(void* const* d_in, const int* in_sizes, int n_in,
                              void* d_out, int out_size, void* d_ws, size_t ws_size,
                              hipStream_t stream) {
    const float* x  = (const float*)d_in[0];
    const float* Wq = (const float*)d_in[1];
    const float* Wk = (const float*)d_in[2];
    const float* Wv = (const float*)d_in[3];
    float* out = (float*)d_out;

    char* w = (char*)d_ws;
    bf16* xb   = (bf16*)(w + XB_OFF);
    bf16* wqb  = (bf16*)(w + WQB_OFF);
    bf16* wkb  = (bf16*)(w + WKB_OFF);
    bf16* wt2  = (bf16*)(w + WT2_OFF);
    float* mtp = (float*)(w + MTP_OFF);
    bf16* yv   = (bf16*)(w + YV_OFF);
    bf16* vt   = (bf16*)(w + VT_OFF);
    bf16* part = (bf16*)(w + PRT_OFF);
    float* stats = (float*)(w + STA_OFF);

    // 1. conversions
    convert_x<<<ROWS * DIN / 4 / 256, 256, 0, stream>>>(x, xb, ROWS * DIN / 4);
    convert_wqk<<<524288 / 256, 256, 0, stream>>>(Wq, Wk, wqb, wkb);
    transpose_wv<<<dim3(2, 16), 256, 0, stream>>>(Wv, wt2);

    // 2. Mt = Wk·Wq^T [512x512] (split-K 8 partials + reduce) -> wt2 rows 0..511
    gemm_mt<<<dim3(4, 4, 8), 256, 0, stream>>>(wkb, wqb, mtp);
    reduce_mt<<<65536 / 256, 256, 0, stream>>>((const float4*)mtp, wt2);

    // 3. yv[8192][640] = xb · wt2^T  (y = x·M fused with v = x·Wv; pad cols garbage, unread)
    gemm_proj<<<dim3(LDY / 128, ROWS / 128, 1), 256, 0, stream>>>(
        xb, wt2, yv, DIN, DIN, DIN, LDY);

    // 3b. vt from yv v-columns
    transpose_v<<<ROWS / 64, 256, 0, stream>>>(yv, vt);

    // 4. fused attention tiles: scores = y·x^T (K=512, 4x less staging), softmax, P~V
    attn_fused<<<dim3(SS / 128 + 1, SS / 256, BB), 512, 0, stream>>>(yv, xb, vt, part, stats);

    // 5. combine partials -> out
    combine<<<ROWS * 8 / 256, 256, 0, stream>>>(part, stats, out);
}